// Round 18
// baseline (169.129 us; speedup 1.0000x reference)
//
#include <hip/hip_runtime.h>
#include <hip/hip_bf16.h>

typedef __bf16 bf16x8 __attribute__((ext_vector_type(8)));
typedef float f32x4 __attribute__((ext_vector_type(4)));
typedef __hip_bfloat16 bf16;

#define B_ 4
#define S_ 2048
#define D_ 1024
#define H_ 16
#define HD_ 64

__device__ __forceinline__ void gload16(const bf16* g, bf16* l) {
  __builtin_amdgcn_global_load_lds(
      (const __attribute__((address_space(1))) unsigned int*)g,
      (__attribute__((address_space(3))) unsigned int*)l, 16, 0, 0);
}

#define MFMA16(a, b, c) __builtin_amdgcn_mfma_f32_16x16x32_bf16((a), (b), (c), 0, 0, 0)

// ---------------------------------------------------------------- cvt f32->bf16 (weights only)
#define NW1_ (3 * D_ * D_)
#define NW2_ (D_ * D_)
__global__ __launch_bounds__(256) void k_cvt2(const float* __restrict__ w1,
                                              const float* __restrict__ w2,
                                              bf16* __restrict__ o1,
                                              bf16* __restrict__ o2) {
  int i = (blockIdx.x * 256 + threadIdx.x) * 4;
  const float* in;
  bf16* out;
  if (i < NW1_) {
    in = w1; out = o1;
  } else {
    in = w2; out = o2; i -= NW1_;
  }
  float4 v = *reinterpret_cast<const float4*>(in + i);
  alignas(8) bf16 t[4];
  t[0] = __float2bfloat16(v.x);
  t[1] = __float2bfloat16(v.y);
  t[2] = __float2bfloat16(v.z);
  t[3] = __float2bfloat16(v.w);
  *reinterpret_cast<uint2*>(out + i) = *reinterpret_cast<uint2*>(t);
}

// ---------------------------------------------------------------- QKV GEMM
// R13 interleaved counted-vmcnt structure, with X read as f32 DIRECTLY
// (cvt fused into A-staging): per tile, A = 4x f32x4 reg loads (issued 2
// tiles ahead) -> cvt -> 2x ds_write_b128 into the buffer freed by
// barrier#2. B stays on gload_lds. Per-iter vm issue order [Bf2,A4,Bl2];
// the A-cvt's auto-wait drains through A(kt+1), so top-of-iter vmcnt(8)
// preserves exactly next tile's B in flight (audited: prologue, steady,
// kt=14/15 tails). sched_barrier(0) pins vm order.
__global__ __launch_bounds__(512) void k_qkv(const float* __restrict__ Xf,
                                             const bf16* __restrict__ W,
                                             bf16* __restrict__ Qw,
                                             bf16* __restrict__ Kw,
                                             bf16* __restrict__ Vtw) {
  __shared__ bf16 Al[2][128 * 64];  // 32 KB
  __shared__ bf16 Bl[2][256 * 64];  // 64 KB
  const int tid = threadIdx.x;
  const int wid = tid >> 6, lane = tid & 63, col = lane & 15, g = lane >> 4;
  const int wr = wid >> 2, wc = wid & 3;
  const int m0 = blockIdx.x * 128, n0 = blockIdx.y * 256;
  // B staging (gload_lds, pre-swizzled source)
  const int srow = tid >> 3;
  const int scol = (tid & 7) * 8;
  const int csrc = scol ^ ((srow & 7) * 8);
  const bf16* gb = W + (size_t)(n0 + srow) * 1024 + csrc;
  const int ldst = srow * 64 + scol;
  // A staging (f32 reg loads + swizzled ds_write): thread -> row ar, 16 f32
  const int ar = tid >> 2, ac4 = tid & 3;
  const float4* gaf =
      reinterpret_cast<const float4*>(Xf + (size_t)(m0 + ar) * 1024) + ac4 * 4;
  const int awoff0 = ar * 64 + (((ac4 * 2 + 0) ^ (ar & 7)) * 8);
  const int awoff1 = ar * 64 + (((ac4 * 2 + 1) ^ (ar & 7)) * 8);
  const int rsw = (col & 7) * 8;
  f32x4 acc[4][4] = {};
  float4 aP[4], aQ[4];

#define A_LOAD(SET, KT)                               \
  do {                                                \
    const int kq = (KT) * 16;                         \
    (SET)[0] = gaf[kq + 0];                           \
    (SET)[1] = gaf[kq + 1];                           \
    (SET)[2] = gaf[kq + 2];                           \
    (SET)[3] = gaf[kq + 3];                           \
  } while (0)
#define A_CVTWRITE(SET, BUF)                          \
  do {                                                \
    alignas(16) bf16 t[16];                           \
    _Pragma("unroll") for (int j = 0; j < 4; ++j) {   \
      t[j * 4 + 0] = __float2bfloat16((SET)[j].x);    \
      t[j * 4 + 1] = __float2bfloat16((SET)[j].y);    \
      t[j * 4 + 2] = __float2bfloat16((SET)[j].z);    \
      t[j * 4 + 3] = __float2bfloat16((SET)[j].w);    \
    }                                                 \
    *reinterpret_cast<int4*>(&Al[BUF][awoff0]) =      \
        *reinterpret_cast<const int4*>(&t[0]);        \
    *reinterpret_cast<int4*>(&Al[BUF][awoff1]) =      \
        *reinterpret_cast<const int4*>(&t[8]);        \
  } while (0)
#define B_GLOAD_F(BUF, K0)                                     \
  do {                                                         \
    gload16(gb + (K0), &Bl[BUF][ldst]);                        \
    gload16(gb + (K0) + 64 * 1024, &Bl[BUF][ldst + 4096]);     \
  } while (0)
#define B_GLOAD_L(BUF, K0)                                     \
  do {                                                         \
    gload16(gb + (K0) + 128 * 1024, &Bl[BUF][ldst + 8192]);    \
    gload16(gb + (K0) + 192 * 1024, &Bl[BUF][ldst + 12288]);   \
  } while (0)

  // prologue: A0 loads, B0 gloads, A1 loads (aP), B1 gloads; cvt+write A0
  A_LOAD(aQ, 0);
  __builtin_amdgcn_sched_barrier(0);
  B_GLOAD_F(0, 0);
  B_GLOAD_L(0, 0);
  __builtin_amdgcn_sched_barrier(0);
  A_LOAD(aP, 1);
  __builtin_amdgcn_sched_barrier(0);
  B_GLOAD_F(1, 64);
  B_GLOAD_L(1, 64);
  __builtin_amdgcn_sched_barrier(0);
  A_CVTWRITE(aQ, 0);  // compiler auto-waits on aQ regs

#define QKV_BODY(KT, AWSET, ALSET)                                            \
  {                                                                           \
    const int c = (KT) & 1;                                                   \
    if ((KT) < 15)                                                            \
      asm volatile("s_waitcnt vmcnt(8) lgkmcnt(0)" ::: "memory");             \
    else                                                                      \
      asm volatile("s_waitcnt vmcnt(0) lgkmcnt(0)" ::: "memory");             \
    __builtin_amdgcn_sched_barrier(0);                                        \
    __builtin_amdgcn_s_barrier();                                             \
    const bf16* Ac = Al[c];                                                   \
    const bf16* Bc = Bl[c];                                                   \
    bf16x8 af[2][4], bfr[2][4];                                               \
    _Pragma("unroll") for (int kk = 0; kk < 2; ++kk) {                        \
      const int ce = (kk * 32 + g * 8) ^ rsw;                                 \
      _Pragma("unroll") for (int m = 0; m < 4; ++m) af[kk][m] =               \
          *reinterpret_cast<const bf16x8*>(                                   \
              &Ac[(wr * 64 + m * 16 + col) * 64 + ce]);                       \
      _Pragma("unroll") for (int n = 0; n < 4; ++n) bfr[kk][n] =              \
          *reinterpret_cast<const bf16x8*>(                                   \
              &Bc[(wc * 64 + n * 16 + col) * 64 + ce]);                       \
    }                                                                         \
    __builtin_amdgcn_s_setprio(1);                                            \
    _Pragma("unroll") for (int m = 0; m < 4; ++m) {                           \
      acc[m][0] = MFMA16(af[0][m], bfr[0][0], acc[m][0]);                     \
      acc[m][1] = MFMA16(af[0][m], bfr[0][1], acc[m][1]);                     \
    }                                                                         \
    __builtin_amdgcn_s_setprio(0);                                            \
    asm volatile("s_waitcnt lgkmcnt(0)" ::: "memory");                        \
    __builtin_amdgcn_sched_barrier(0);                                        \
    __builtin_amdgcn_s_barrier();                                             \
    if ((KT) + 2 < 16) {                                                      \
      B_GLOAD_F(c, ((KT) + 2) * 64);                                          \
      __builtin_amdgcn_sched_barrier(0);                                      \
    }                                                                         \
    __builtin_amdgcn_s_setprio(1);                                            \
    _Pragma("unroll") for (int m = 0; m < 4; ++m) {                           \
      acc[m][2] = MFMA16(af[0][m], bfr[0][2], acc[m][2]);                     \
      acc[m][3] = MFMA16(af[0][m], bfr[0][3], acc[m][3]);                     \
    }                                                                         \
    __builtin_amdgcn_s_setprio(0);                                            \
    if ((KT) + 1 < 16) { A_CVTWRITE(AWSET, c ^ 1); }                          \
    __builtin_amdgcn_s_setprio(1);                                            \
    _Pragma("unroll") for (int m = 0; m < 4; ++m) {                           \
      acc[m][0] = MFMA16(af[1][m], bfr[1][0], acc[m][0]);                     \
      acc[m][1] = MFMA16(af[1][m], bfr[1][1], acc[m][1]);                     \
    }                                                                         \
    __builtin_amdgcn_s_setprio(0);                                            \
    if ((KT) + 2 < 16) {                                                      \
      A_LOAD(ALSET, (KT) + 2);                                                \
      __builtin_amdgcn_sched_barrier(0);                                      \
      B_GLOAD_L(c, ((KT) + 2) * 64);                                          \
      __builtin_amdgcn_sched_barrier(0);                                      \
    }                                                                         \
    __builtin_amdgcn_s_setprio(1);                                            \
    _Pragma("unroll") for (int m = 0; m < 4; ++m) {                           \
      acc[m][2] = MFMA16(af[1][m], bfr[1][2], acc[m][2]);                     \
      acc[m][3] = MFMA16(af[1][m], bfr[1][3], acc[m][3]);                     \
    }                                                                         \
    __builtin_amdgcn_s_setprio(0);                                            \
  }

  for (int ktp = 0; ktp < 8; ++ktp) {
    QKV_BODY(2 * ktp, aP, aQ);
    QKV_BODY(2 * ktp + 1, aQ, aP);
  }
#undef QKV_BODY
#undef A_LOAD
#undef A_CVTWRITE
#undef B_GLOAD_F
#undef B_GLOAD_L

  const int e0 = n0 + wc * 64;
  const int which = e0 >> 10;
  const int h = (e0 >> 6) & 15;
  if (which == 2) {
#pragma unroll
    for (int m = 0; m < 4; ++m) {
      int mg = m0 + wr * 64 + m * 16 + g * 4;
      int b = mg >> 11, s = mg & 2047;
#pragma unroll
      for (int n = 0; n < 4; ++n) {
        int d = n * 16 + col;
        alignas(8) bf16 t[4];
#pragma unroll
        for (int r = 0; r < 4; ++r) t[r] = __float2bfloat16(acc[m][n][r]);
        *reinterpret_cast<uint2*>(&Vtw[((size_t)((b * 16 + h) * 64 + d) << 11) + s]) =
            *reinterpret_cast<uint2*>(t);
      }
    }
  } else {
    bf16* dst = which ? Kw : Qw;
    const float scale = which ? 1.0f : 0.18033688011112042f;  // 0.125*log2(e)
    const float fexp = -2.0f * 13.287712379549449f / 64.0f;
#pragma unroll
    for (int i = 0; i < 2; ++i) {
      int dlo = i * 16 + col;
      float invf = exp2f(fexp * (float)dlo);
#pragma unroll
      for (int m = 0; m < 4; ++m) {
        int mg = m0 + wr * 64 + m * 16 + g * 4;
        int b = mg >> 11;
        size_t rb = (size_t)(b * 16 + h) << 11;
#pragma unroll
        for (int r = 0; r < 4; ++r) {
          int s = (mg + r) & 2047;
          float sn, cs;
          __sincosf((float)s * invf, &sn, &cs);
          float lo = acc[m][i][r] * scale, hi = acc[m][i + 2][r] * scale;
          dst[((rb + s) << 6) + dlo] = __float2bfloat16(lo * cs - hi * sn);
          dst[((rb + s) << 6) + dlo + 32] = __float2bfloat16(hi * cs + lo * sn);
        }
      }
    }
  }
}

// ---------------------------------------------------------------- flash attention (R16 winner, restored)
// gload_lds -> double-buffered K/V (linear stride 64, both-sides XOR
// swizzle), counted vmcnt(2), raw s_barrier, stage kt+2 after consume
// barrier. Q fragments from global (one-time). P pad-72. LDS 50KB.
__global__ __launch_bounds__(512) void k_attn(const bf16* __restrict__ Q,
                                              const bf16* __restrict__ K,
                                              const bf16* __restrict__ Vt,
                                              bf16* __restrict__ AO) {
  __shared__ bf16 Pl[128][72];
  __shared__ bf16 Kl[2][64 * 64];
  __shared__ bf16 Vl[2][64 * 64];
  const int tid = threadIdx.x;
  const int wave = tid >> 6, lane = tid & 63, col = lane & 15, g = lane >> 4;
  const int bh = blockIdx.x;
  const size_t base = (size_t)bh << 17;
  const int r0 = tid >> 3, c0 = (tid & 7) * 8;
  const int c0s = c0 ^ ((r0 & 7) * 8);
  const int ldst = r0 * 64 + c0;
  const int swc = (col & 7) * 8;
  const int b = bh >> 4, h = bh & 15;
  const int yy = blockIdx.y, a = yy >> 2, r_ = yy & 3;
  const int qt = (a == 0) ? (15 - r_) : (a == 1) ? (8 + (r_ ^ 2)) : (a == 2) ? (4 + (r_ ^ 1)) : r_;
  const int q0 = qt * 128;
  const int qw = q0 + wave * 16;
  const int q = qw + col;
  const bf16* Qp = Q + base + (size_t)q * 64 + g * 8;
  bf16x8 qf[2];
  qf[0] = *reinterpret_cast<const bf16x8*>(Qp);
  qf[1] = *reinterpret_cast<const bf16x8*>(Qp + 32);
  const int ktlim = 2 * qt + 1;
  const int ktmax = (qw + 15) >> 6;
  const bf16* Ks = K + base + c0s;
  const bf16* Vs = Vt + base + (size_t)r0 * 2048 + c0s;
#define ATT_STAGE(buf, k0)                                  \
  do {                                                      \
    gload16(Ks + (size_t)((k0) + r0) * 64, &Kl[buf][ldst]); \
    gload16(Vs + (k0), &Vl[buf][ldst]);                     \
  } while (0)
  ATT_STAGE(0, 0);
  ATT_STAGE(1, 64);
  float l_s = 0.0f;
  f32x4 o[4] = {};
  for (int kt = 0; kt <= ktlim; ++kt) {
    const int c = kt & 1;
    const int k0 = kt * 64;
    if (kt < ktlim)
      asm volatile("s_waitcnt vmcnt(2)" ::: "memory");
    else
      asm volatile("s_waitcnt vmcnt(0)" ::: "memory");
    __builtin_amdgcn_s_barrier();
    if (kt <= ktmax) {
      const bool needmask = (k0 + 63 > qw);
      __builtin_amdgcn_s_setprio(1);
#pragma unroll
      for (int n = 0; n < 4; ++n) {
        f32x4 s = {};
#pragma unroll
        for (int kk = 0; kk < 2; ++kk) {
          bf16x8 kf = *reinterpret_cast<const bf16x8*>(
              &Kl[c][(n * 16 + col) * 64 + ((g * 8 + kk * 32) ^ swc)]);
          s = MFMA16(kf, qf[kk], s);
        }
        if (needmask) {
#pragma unroll
          for (int r = 0; r < 4; ++r)
            if (k0 + n * 16 + g * 4 + r > q) s[r] = -3e38f;
        }
        alignas(8) bf16 t[4];
#pragma unroll
        for (int r = 0; r < 4; ++r) {
          float p = exp2f(s[r]);
          l_s += p;
          t[r] = __float2bfloat16(p);
        }
        *reinterpret_cast<uint2*>(&Pl[wave * 16 + col][n * 16 + g * 4]) =
            *reinterpret_cast<uint2*>(t);
      }
#pragma unroll
      for (int kk = 0; kk < 2; ++kk) {
        bf16x8 pf =
            *reinterpret_cast<const bf16x8*>(&Pl[wave * 16 + col][g * 8 + kk * 32]);
#pragma unroll
        for (int n2 = 0; n2 < 4; ++n2) {
          bf16x8 vf = *reinterpret_cast<const bf16x8*>(
              &Vl[c][(n2 * 16 + col) * 64 + ((g * 8 + kk * 32) ^ swc)]);
          o[n2] = MFMA16(pf, vf, o[n2]);
        }
      }
      __builtin_amdgcn_s_setprio(0);
    }
    __builtin_amdgcn_s_barrier();
    if (kt + 2 <= ktlim) ATT_STAGE(c, k0 + 128);
  }
#undef ATT_STAGE
  l_s += __shfl_xor(l_s, 16);
  l_s += __shfl_xor(l_s, 32);
#pragma unroll
  for (int r = 0; r < 4; ++r) {
    float inv = 1.0f / __shfl(l_s, (lane & 48) | (g * 4 + r));
    int s = qw + g * 4 + r;
#pragma unroll
    for (int n2 = 0; n2 < 4; ++n2)
      AO[((size_t)(b * 2048 + s) << 10) + h * 64 + n2 * 16 + col] =
          __float2bfloat16(o[n2][r] * inv);
  }
}

// ---------------------------------------------------------------- out projection (R13: interleaved counted-vmcnt)
__global__ __launch_bounds__(512) void k_outproj(const bf16* __restrict__ A,
                                                 const bf16* __restrict__ W,
                                                 float* __restrict__ OUT) {
  __shared__ bf16 Al[2][128 * 64];
  __shared__ bf16 Bl[2][256 * 64];
  const int tid = threadIdx.x;
  const int wid = tid >> 6, lane = tid & 63, col = lane & 15, g = lane >> 4;
  const int wr = wid >> 2, wc = wid & 3;
  const int m0 = blockIdx.x * 128, n0 = blockIdx.y * 256;
  const int srow = tid >> 3;
  const int scol = (tid & 7) * 8;
  const int csrc = scol ^ ((srow & 7) * 8);
  const bf16* ga = A + (size_t)(m0 + srow) * 1024 + csrc;
  const bf16* gb = W + (size_t)(n0 + srow) * 1024 + csrc;
  const int ldst = srow * 64 + scol;
  const int rsw = (col & 7) * 8;
  f32x4 acc[4][4] = {};
#define OP_STAGE_ALL(buf, k0)                                \
  do {                                                       \
    gload16(ga + (k0), &Al[buf][ldst]);                      \
    gload16(ga + (k0) + 64 * 1024, &Al[buf][ldst + 4096]);   \
    gload16(gb + (k0), &Bl[buf][ldst]);                      \
    gload16(gb + (k0) + 64 * 1024, &Bl[buf][ldst + 4096]);   \
    gload16(gb + (k0) + 128 * 1024, &Bl[buf][ldst + 8192]);  \
    gload16(gb + (k0) + 192 * 1024, &Bl[buf][ldst + 12288]); \
  } while (0)
  OP_STAGE_ALL(0, 0);
  OP_STAGE_ALL(1, 64);
  for (int kt = 0; kt < 16; ++kt) {
    const int c = kt & 1;
    if (kt < 15)
      asm volatile("s_waitcnt vmcnt(6)" ::: "memory");
    else
      asm volatile("s_waitcnt vmcnt(0)" ::: "memory");
    __builtin_amdgcn_s_barrier();
    const bf16* Ac = Al[c];
    const bf16* Bc = Bl[c];
    bf16x8 af[2][4], bfr[2][4];
#pragma unroll
    for (int kk = 0; kk < 2; ++kk) {
      const int ce = (kk * 32 + g * 8) ^ rsw;
#pragma unroll
      for (int m = 0; m < 4; ++m)
        af[kk][m] =
            *reinterpret_cast<const bf16x8*>(&Ac[(wr * 64 + m * 16 + col) * 64 + ce]);
#pragma unroll
      for (int n = 0; n < 4; ++n)
        bfr[kk][n] =
            *reinterpret_cast<const bf16x8*>(&Bc[(wc * 64 + n * 16 + col) * 64 + ce]);
    }
    __builtin_amdgcn_s_setprio(1);
#pragma unroll
    for (int m = 0; m < 4; ++m) {
      acc[m][0] = MFMA16(af[0][m], bfr[0][0], acc[m][0]);
      acc[m][1] = MFMA16(af[0][m], bfr[0][1], acc[m][1]);
    }
    __builtin_amdgcn_s_setprio(0);
    asm volatile("s_waitcnt lgkmcnt(0)" ::: "memory");
    __builtin_amdgcn_sched_barrier(0);
    __builtin_amdgcn_s_barrier();
    const bool more = (kt + 2 < 16);
    const int k2 = (kt + 2) * 64;
    if (more) {
      gload16(ga + k2, &Al[c][ldst]);
      gload16(ga + k2 + 64 * 1024, &Al[c][ldst + 4096]);
    }
    __builtin_amdgcn_s_setprio(1);
#pragma unroll
    for (int m = 0; m < 4; ++m) {
      acc[m][2] = MFMA16(af[0][m], bfr[0][2], acc[m][2]);
      acc[m][3] = MFMA16(af[0][m], bfr[0][3], acc[m][3]);
    }
    __builtin_amdgcn_s_setprio(0);
    if (more) {
      gload16(gb + k2, &Bl[c][ldst]);
      gload16(gb + k2 + 64 * 1024, &Bl[c][ldst + 4096]);
    }
    __builtin_amdgcn_s_setprio(1);
#pragma unroll
    for (int m = 0; m < 4; ++m) {
      acc[m][0] = MFMA16(af[1][m], bfr[1][0], acc[m][0]);
      acc[m][1] = MFMA16(af[1][m], bfr[1][1], acc[m][1]);
    }
    __builtin_amdgcn_s_setprio(0);
    if (more) {
      gload16(gb + k2 + 128 * 1024, &Bl[c][ldst + 8192]);
      gload16(gb + k2 + 192 * 1024, &Bl[c][ldst + 12288]);
    }
    __builtin_amdgcn_s_setprio(1);
#pragma unroll
    for (int m = 0; m < 4; ++m) {
      acc[m][2] = MFMA16(af[1][m], bfr[1][2], acc[m][2]);
      acc[m][3] = MFMA16(af[1][m], bfr[1][3], acc[m][3]);
    }
    __builtin_amdgcn_s_setprio(0);
  }
#undef OP_STAGE_ALL
#pragma unroll
  for (int m = 0; m < 4; ++m)
#pragma unroll
    for (int n = 0; n < 4; ++n)
#pragma unroll
      for (int r = 0; r < 4; ++r)
        OUT[(size_t)(m0 + wr * 64 + m * 16 + g * 4 + r) * 1024 + n0 + wc * 64 + n * 16 +
            col] = acc[m][n][r];
}

// ---------------------------------------------------------------- launcher
extern "C" void kernel_launch(void* const* d_in, const int* in_sizes, int n_in,
                              void* d_out, int out_size, void* d_ws, size_t ws_size,
                              hipStream_t stream) {
  const float* x = (const float*)d_in[0];
  const float* wqkv = (const float*)d_in[1];
  const float* wout = (const float*)d_in[2];
  float* out = (float*)d_out;

  char* ws = (char*)d_ws;
  const size_t SZ_X = (size_t)B_ * S_ * D_ * 2;  // region kept (unused) for layout stability
  const size_t SZ_WQKV = (size_t)3 * D_ * D_ * 2;
  const size_t SZ_WOUT = (size_t)D_ * D_ * 2;
  const size_t SZ_T = (size_t)B_ * H_ * S_ * HD_ * 2;
  bf16* wqkvb = (bf16*)(ws + SZ_X);
  bf16* woutb = (bf16*)(ws + SZ_X + SZ_WQKV);
  bf16* qws = (bf16*)(ws + SZ_X + SZ_WQKV + SZ_WOUT);
  bf16* kws = (bf16*)(ws + SZ_X + SZ_WQKV + SZ_WOUT + SZ_T);
  bf16* vtws = (bf16*)(ws + SZ_X + SZ_WQKV + SZ_WOUT + 2 * SZ_T);
  bf16* aob = (bf16*)(ws + SZ_X + SZ_WQKV + SZ_WOUT + 3 * SZ_T);

  const int NTOT4 = (NW1_ + NW2_) / 4;
  k_cvt2<<<NTOT4 / 256, 256, 0, stream>>>(wqkv, wout, wqkvb, woutb);

  k_qkv<<<dim3(64, 12), 512, 0, stream>>>(x, wqkvb, qws, kws, vtws);
  k_attn<<<dim3(B_ * H_, 16), 512, 0, stream>>>(qws, kws, vtws, aob);
  k_outproj<<<dim3(64, 4), 512, 0, stream>>>(aob, woutb, out);
}

// Round 19
// 163.524 us; speedup vs baseline: 1.0343x; 1.0343x over previous
//
#include <hip/hip_runtime.h>
#include <hip/hip_bf16.h>

typedef __bf16 bf16x8 __attribute__((ext_vector_type(8)));
typedef float f32x4 __attribute__((ext_vector_type(4)));
typedef __hip_bfloat16 bf16;

#define B_ 4
#define S_ 2048
#define D_ 1024
#define H_ 16
#define HD_ 64

__device__ __forceinline__ void gload16(const bf16* g, bf16* l) {
  __builtin_amdgcn_global_load_lds(
      (const __attribute__((address_space(1))) unsigned int*)g,
      (__attribute__((address_space(3))) unsigned int*)l, 16, 0, 0);
}

#define MFMA16(a, b, c) __builtin_amdgcn_mfma_f32_16x16x32_bf16((a), (b), (c), 0, 0, 0)

// ---------------------------------------------------------------- cvt f32->bf16 (fused x, w_qkv, w_out)
#define NX_ (B_ * S_ * D_)
#define NW1_ (3 * D_ * D_)
#define NW2_ (D_ * D_)
__global__ __launch_bounds__(256) void k_cvt3(const float* __restrict__ x,
                                              const float* __restrict__ w1,
                                              const float* __restrict__ w2,
                                              bf16* __restrict__ ox,
                                              bf16* __restrict__ o1,
                                              bf16* __restrict__ o2) {
  int i = (blockIdx.x * 256 + threadIdx.x) * 4;
  const float* in;
  bf16* out;
  if (i < NX_) {
    in = x; out = ox;
  } else if (i < NX_ + NW1_) {
    in = w1; out = o1; i -= NX_;
  } else {
    in = w2; out = o2; i -= NX_ + NW1_;
  }
  float4 v = *reinterpret_cast<const float4*>(in + i);
  alignas(8) bf16 t[4];
  t[0] = __float2bfloat16(v.x);
  t[1] = __float2bfloat16(v.y);
  t[2] = __float2bfloat16(v.z);
  t[3] = __float2bfloat16(v.w);
  *reinterpret_cast<uint2*>(out + i) = *reinterpret_cast<uint2*>(t);
}

// ---------------------------------------------------------------- QKV GEMM (R13: interleaved counted-vmcnt)
__global__ __launch_bounds__(512) void k_qkv(const bf16* __restrict__ X,
                                             const bf16* __restrict__ W,
                                             bf16* __restrict__ Qw,
                                             bf16* __restrict__ Kw,
                                             bf16* __restrict__ Vtw) {
  __shared__ bf16 Al[2][128 * 64];  // 32 KB
  __shared__ bf16 Bl[2][256 * 64];  // 64 KB
  const int tid = threadIdx.x;
  const int wid = tid >> 6, lane = tid & 63, col = lane & 15, g = lane >> 4;
  const int wr = wid >> 2, wc = wid & 3;
  const int m0 = blockIdx.x * 128, n0 = blockIdx.y * 256;
  const int srow = tid >> 3;                 // 0..63
  const int scol = (tid & 7) * 8;
  const int csrc = scol ^ ((srow & 7) * 8);  // pre-swizzled source col
  const bf16* ga = X + (size_t)(m0 + srow) * 1024 + csrc;
  const bf16* gb = W + (size_t)(n0 + srow) * 1024 + csrc;
  const int ldst = srow * 64 + scol;         // linear LDS dest
  const int rsw = (col & 7) * 8;
  f32x4 acc[4][4] = {};
#define QKV_STAGE_ALL(buf, k0)                               \
  do {                                                       \
    gload16(ga + (k0), &Al[buf][ldst]);                      \
    gload16(ga + (k0) + 64 * 1024, &Al[buf][ldst + 4096]);   \
    gload16(gb + (k0), &Bl[buf][ldst]);                      \
    gload16(gb + (k0) + 64 * 1024, &Bl[buf][ldst + 4096]);   \
    gload16(gb + (k0) + 128 * 1024, &Bl[buf][ldst + 8192]);  \
    gload16(gb + (k0) + 192 * 1024, &Bl[buf][ldst + 12288]); \
  } while (0)
  QKV_STAGE_ALL(0, 0);
  QKV_STAGE_ALL(1, 64);
  for (int kt = 0; kt < 16; ++kt) {
    const int c = kt & 1;
    if (kt < 15)
      asm volatile("s_waitcnt vmcnt(6)" ::: "memory");
    else
      asm volatile("s_waitcnt vmcnt(0)" ::: "memory");
    __builtin_amdgcn_s_barrier();  // tile kt landed for all waves
    const bf16* Ac = Al[c];
    const bf16* Bc = Bl[c];
    bf16x8 af[2][4], bfr[2][4];
#pragma unroll
    for (int kk = 0; kk < 2; ++kk) {
      const int ce = (kk * 32 + g * 8) ^ rsw;
#pragma unroll
      for (int m = 0; m < 4; ++m)
        af[kk][m] =
            *reinterpret_cast<const bf16x8*>(&Ac[(wr * 64 + m * 16 + col) * 64 + ce]);
#pragma unroll
      for (int n = 0; n < 4; ++n)
        bfr[kk][n] =
            *reinterpret_cast<const bf16x8*>(&Bc[(wc * 64 + n * 16 + col) * 64 + ce]);
    }
    __builtin_amdgcn_s_setprio(1);
#pragma unroll
    for (int m = 0; m < 4; ++m) {
      acc[m][0] = MFMA16(af[0][m], bfr[0][0], acc[m][0]);
      acc[m][1] = MFMA16(af[0][m], bfr[0][1], acc[m][1]);
    }
    __builtin_amdgcn_s_setprio(0);
    asm volatile("s_waitcnt lgkmcnt(0)" ::: "memory");
    __builtin_amdgcn_sched_barrier(0);
    __builtin_amdgcn_s_barrier();  // all waves' reads of buf c complete -> free
    const bool more = (kt + 2 < 16);
    const int k2 = (kt + 2) * 64;
    if (more) {
      gload16(ga + k2, &Al[c][ldst]);
      gload16(ga + k2 + 64 * 1024, &Al[c][ldst + 4096]);
    }
    __builtin_amdgcn_s_setprio(1);
#pragma unroll
    for (int m = 0; m < 4; ++m) {
      acc[m][2] = MFMA16(af[0][m], bfr[0][2], acc[m][2]);
      acc[m][3] = MFMA16(af[0][m], bfr[0][3], acc[m][3]);
    }
    __builtin_amdgcn_s_setprio(0);
    if (more) {
      gload16(gb + k2, &Bl[c][ldst]);
      gload16(gb + k2 + 64 * 1024, &Bl[c][ldst + 4096]);
    }
    __builtin_amdgcn_s_setprio(1);
#pragma unroll
    for (int m = 0; m < 4; ++m) {
      acc[m][0] = MFMA16(af[1][m], bfr[1][0], acc[m][0]);
      acc[m][1] = MFMA16(af[1][m], bfr[1][1], acc[m][1]);
    }
    __builtin_amdgcn_s_setprio(0);
    if (more) {
      gload16(gb + k2 + 128 * 1024, &Bl[c][ldst + 8192]);
      gload16(gb + k2 + 192 * 1024, &Bl[c][ldst + 12288]);
    }
    __builtin_amdgcn_s_setprio(1);
#pragma unroll
    for (int m = 0; m < 4; ++m) {
      acc[m][2] = MFMA16(af[1][m], bfr[1][2], acc[m][2]);
      acc[m][3] = MFMA16(af[1][m], bfr[1][3], acc[m][3]);
    }
    __builtin_amdgcn_s_setprio(0);
  }
#undef QKV_STAGE_ALL
  const int e0 = n0 + wc * 64;
  const int which = e0 >> 10;
  const int h = (e0 >> 6) & 15;
  if (which == 2) {
#pragma unroll
    for (int m = 0; m < 4; ++m) {
      int mg = m0 + wr * 64 + m * 16 + g * 4;
      int b = mg >> 11, s = mg & 2047;
#pragma unroll
      for (int n = 0; n < 4; ++n) {
        int d = n * 16 + col;
        alignas(8) bf16 t[4];
#pragma unroll
        for (int r = 0; r < 4; ++r) t[r] = __float2bfloat16(acc[m][n][r]);
        *reinterpret_cast<uint2*>(&Vtw[((size_t)((b * 16 + h) * 64 + d) << 11) + s]) =
            *reinterpret_cast<uint2*>(t);
      }
    }
  } else {
    bf16* dst = which ? Kw : Qw;
    const float scale = which ? 1.0f : 0.18033688011112042f;  // 0.125*log2(e)
    const float fexp = -2.0f * 13.287712379549449f / 64.0f;
#pragma unroll
    for (int i = 0; i < 2; ++i) {
      int dlo = i * 16 + col;
      float invf = exp2f(fexp * (float)dlo);
#pragma unroll
      for (int m = 0; m < 4; ++m) {
        int mg = m0 + wr * 64 + m * 16 + g * 4;
        int b = mg >> 11;
        size_t rb = (size_t)(b * 16 + h) << 11;
#pragma unroll
        for (int r = 0; r < 4; ++r) {
          int s = (mg + r) & 2047;
          float sn, cs;
          __sincosf((float)s * invf, &sn, &cs);
          float lo = acc[m][i][r] * scale, hi = acc[m][i + 2][r] * scale;
          dst[((rb + s) << 6) + dlo] = __float2bfloat16(lo * cs - hi * sn);
          dst[((rb + s) << 6) + dlo + 32] = __float2bfloat16(hi * cs + lo * sn);
        }
      }
    }
  }
}

// ---------------------------------------------------------------- flash attention (R16 winner + f32x4 l-acc)
// gload_lds -> double-buffered K/V (linear stride 64, both-sides XOR
// swizzle), counted vmcnt(2), raw s_barrier, stage kt+2 after consume
// barrier. Q fragments from global (one-time). P pad-72. LDS 50KB.
__global__ __launch_bounds__(512) void k_attn(const bf16* __restrict__ Q,
                                              const bf16* __restrict__ K,
                                              const bf16* __restrict__ Vt,
                                              bf16* __restrict__ AO) {
  __shared__ bf16 Pl[128][72];
  __shared__ bf16 Kl[2][64 * 64];
  __shared__ bf16 Vl[2][64 * 64];
  const int tid = threadIdx.x;
  const int wave = tid >> 6, lane = tid & 63, col = lane & 15, g = lane >> 4;
  const int bh = blockIdx.x;
  const size_t base = (size_t)bh << 17;
  const int r0 = tid >> 3, c0 = (tid & 7) * 8;
  const int c0s = c0 ^ ((r0 & 7) * 8);
  const int ldst = r0 * 64 + c0;
  const int swc = (col & 7) * 8;
  const int b = bh >> 4, h = bh & 15;
  const int yy = blockIdx.y, a = yy >> 2, r_ = yy & 3;
  const int qt = (a == 0) ? (15 - r_) : (a == 1) ? (8 + (r_ ^ 2)) : (a == 2) ? (4 + (r_ ^ 1)) : r_;
  const int q0 = qt * 128;
  const int qw = q0 + wave * 16;
  const int q = qw + col;
  const bf16* Qp = Q + base + (size_t)q * 64 + g * 8;
  bf16x8 qf[2];
  qf[0] = *reinterpret_cast<const bf16x8*>(Qp);
  qf[1] = *reinterpret_cast<const bf16x8*>(Qp + 32);
  const int ktlim = 2 * qt + 1;
  const int ktmax = (qw + 15) >> 6;
  const bf16* Ks = K + base + c0s;
  const bf16* Vs = Vt + base + (size_t)r0 * 2048 + c0s;
#define ATT_STAGE(buf, k0)                                  \
  do {                                                      \
    gload16(Ks + (size_t)((k0) + r0) * 64, &Kl[buf][ldst]); \
    gload16(Vs + (k0), &Vl[buf][ldst]);                     \
  } while (0)
  ATT_STAGE(0, 0);
  ATT_STAGE(1, 64);
  f32x4 lacc = {};
  f32x4 o[4] = {};
  for (int kt = 0; kt <= ktlim; ++kt) {
    const int c = kt & 1;
    const int k0 = kt * 64;
    if (kt < ktlim)
      asm volatile("s_waitcnt vmcnt(2)" ::: "memory");
    else
      asm volatile("s_waitcnt vmcnt(0)" ::: "memory");
    __builtin_amdgcn_s_barrier();
    if (kt <= ktmax) {
      const bool needmask = (k0 + 63 > qw);
      __builtin_amdgcn_s_setprio(1);
#pragma unroll
      for (int n = 0; n < 4; ++n) {
        f32x4 s = {};
#pragma unroll
        for (int kk = 0; kk < 2; ++kk) {
          bf16x8 kf = *reinterpret_cast<const bf16x8*>(
              &Kl[c][(n * 16 + col) * 64 + ((g * 8 + kk * 32) ^ swc)]);
          s = MFMA16(kf, qf[kk], s);
        }
        if (needmask) {
#pragma unroll
          for (int r = 0; r < 4; ++r)
            if (k0 + n * 16 + g * 4 + r > q) s[r] = -3e38f;
        }
        alignas(8) bf16 t[4];
#pragma unroll
        for (int r = 0; r < 4; ++r) {
          float p = exp2f(s[r]);
          lacc[r] += p;
          t[r] = __float2bfloat16(p);
        }
        *reinterpret_cast<uint2*>(&Pl[wave * 16 + col][n * 16 + g * 4]) =
            *reinterpret_cast<uint2*>(t);
      }
#pragma unroll
      for (int kk = 0; kk < 2; ++kk) {
        bf16x8 pf =
            *reinterpret_cast<const bf16x8*>(&Pl[wave * 16 + col][g * 8 + kk * 32]);
#pragma unroll
        for (int n2 = 0; n2 < 4; ++n2) {
          bf16x8 vf = *reinterpret_cast<const bf16x8*>(
              &Vl[c][(n2 * 16 + col) * 64 + ((g * 8 + kk * 32) ^ swc)]);
          o[n2] = MFMA16(pf, vf, o[n2]);
        }
      }
      __builtin_amdgcn_s_setprio(0);
    }
    __builtin_amdgcn_s_barrier();
    if (kt + 2 <= ktlim) ATT_STAGE(c, k0 + 128);
  }
#undef ATT_STAGE
  float l_s = (lacc[0] + lacc[1]) + (lacc[2] + lacc[3]);
  l_s += __shfl_xor(l_s, 16);
  l_s += __shfl_xor(l_s, 32);
#pragma unroll
  for (int r = 0; r < 4; ++r) {
    float inv = 1.0f / __shfl(l_s, (lane & 48) | (g * 4 + r));
    int s = qw + g * 4 + r;
#pragma unroll
    for (int n2 = 0; n2 < 4; ++n2)
      AO[((size_t)(b * 2048 + s) << 10) + h * 64 + n2 * 16 + col] =
          __float2bfloat16(o[n2][r] * inv);
  }
}

// ---------------------------------------------------------------- out projection (R13: interleaved counted-vmcnt)
__global__ __launch_bounds__(512) void k_outproj(const bf16* __restrict__ A,
                                                 const bf16* __restrict__ W,
                                                 float* __restrict__ OUT) {
  __shared__ bf16 Al[2][128 * 64];
  __shared__ bf16 Bl[2][256 * 64];
  const int tid = threadIdx.x;
  const int wid = tid >> 6, lane = tid & 63, col = lane & 15, g = lane >> 4;
  const int wr = wid >> 2, wc = wid & 3;
  const int m0 = blockIdx.x * 128, n0 = blockIdx.y * 256;
  const int srow = tid >> 3;
  const int scol = (tid & 7) * 8;
  const int csrc = scol ^ ((srow & 7) * 8);
  const bf16* ga = A + (size_t)(m0 + srow) * 1024 + csrc;
  const bf16* gb = W + (size_t)(n0 + srow) * 1024 + csrc;
  const int ldst = srow * 64 + scol;
  const int rsw = (col & 7) * 8;
  f32x4 acc[4][4] = {};
#define OP_STAGE_ALL(buf, k0)                                \
  do {                                                       \
    gload16(ga + (k0), &Al[buf][ldst]);                      \
    gload16(ga + (k0) + 64 * 1024, &Al[buf][ldst + 4096]);   \
    gload16(gb + (k0), &Bl[buf][ldst]);                      \
    gload16(gb + (k0) + 64 * 1024, &Bl[buf][ldst + 4096]);   \
    gload16(gb + (k0) + 128 * 1024, &Bl[buf][ldst + 8192]);  \
    gload16(gb + (k0) + 192 * 1024, &Bl[buf][ldst + 12288]); \
  } while (0)
  OP_STAGE_ALL(0, 0);
  OP_STAGE_ALL(1, 64);
  for (int kt = 0; kt < 16; ++kt) {
    const int c = kt & 1;
    if (kt < 15)
      asm volatile("s_waitcnt vmcnt(6)" ::: "memory");
    else
      asm volatile("s_waitcnt vmcnt(0)" ::: "memory");
    __builtin_amdgcn_s_barrier();
    const bf16* Ac = Al[c];
    const bf16* Bc = Bl[c];
    bf16x8 af[2][4], bfr[2][4];
#pragma unroll
    for (int kk = 0; kk < 2; ++kk) {
      const int ce = (kk * 32 + g * 8) ^ rsw;
#pragma unroll
      for (int m = 0; m < 4; ++m)
        af[kk][m] =
            *reinterpret_cast<const bf16x8*>(&Ac[(wr * 64 + m * 16 + col) * 64 + ce]);
#pragma unroll
      for (int n = 0; n < 4; ++n)
        bfr[kk][n] =
            *reinterpret_cast<const bf16x8*>(&Bc[(wc * 64 + n * 16 + col) * 64 + ce]);
    }
    __builtin_amdgcn_s_setprio(1);
#pragma unroll
    for (int m = 0; m < 4; ++m) {
      acc[m][0] = MFMA16(af[0][m], bfr[0][0], acc[m][0]);
      acc[m][1] = MFMA16(af[0][m], bfr[0][1], acc[m][1]);
    }
    __builtin_amdgcn_s_setprio(0);
    asm volatile("s_waitcnt lgkmcnt(0)" ::: "memory");
    __builtin_amdgcn_sched_barrier(0);
    __builtin_amdgcn_s_barrier();
    const bool more = (kt + 2 < 16);
    const int k2 = (kt + 2) * 64;
    if (more) {
      gload16(ga + k2, &Al[c][ldst]);
      gload16(ga + k2 + 64 * 1024, &Al[c][ldst + 4096]);
    }
    __builtin_amdgcn_s_setprio(1);
#pragma unroll
    for (int m = 0; m < 4; ++m) {
      acc[m][2] = MFMA16(af[0][m], bfr[0][2], acc[m][2]);
      acc[m][3] = MFMA16(af[0][m], bfr[0][3], acc[m][3]);
    }
    __builtin_amdgcn_s_setprio(0);
    if (more) {
      gload16(gb + k2, &Bl[c][ldst]);
      gload16(gb + k2 + 64 * 1024, &Bl[c][ldst + 4096]);
    }
    __builtin_amdgcn_s_setprio(1);
#pragma unroll
    for (int m = 0; m < 4; ++m) {
      acc[m][0] = MFMA16(af[1][m], bfr[1][0], acc[m][0]);
      acc[m][1] = MFMA16(af[1][m], bfr[1][1], acc[m][1]);
    }
    __builtin_amdgcn_s_setprio(0);
    if (more) {
      gload16(gb + k2 + 128 * 1024, &Bl[c][ldst + 8192]);
      gload16(gb + k2 + 192 * 1024, &Bl[c][ldst + 12288]);
    }
    __builtin_amdgcn_s_setprio(1);
#pragma unroll
    for (int m = 0; m < 4; ++m) {
      acc[m][2] = MFMA16(af[1][m], bfr[1][2], acc[m][2]);
      acc[m][3] = MFMA16(af[1][m], bfr[1][3], acc[m][3]);
    }
    __builtin_amdgcn_s_setprio(0);
  }
#undef OP_STAGE_ALL
#pragma unroll
  for (int m = 0; m < 4; ++m)
#pragma unroll
    for (int n = 0; n < 4; ++n)
#pragma unroll
      for (int r = 0; r < 4; ++r)
        OUT[(size_t)(m0 + wr * 64 + m * 16 + g * 4 + r) * 1024 + n0 + wc * 64 + n * 16 +
            col] = acc[m][n][r];
}

// ---------------------------------------------------------------- launcher
extern "C" void kernel_launch(void* const* d_in, const int* in_sizes, int n_in,
                              void* d_out, int out_size, void* d_ws, size_t ws_size,
                              hipStream_t stream) {
  const float* x = (const float*)d_in[0];
  const float* wqkv = (const float*)d_in[1];
  const float* wout = (const float*)d_in[2];
  float* out = (float*)d_out;

  char* ws = (char*)d_ws;
  const size_t SZ_X = (size_t)B_ * S_ * D_ * 2;
  const size_t SZ_WQKV = (size_t)3 * D_ * D_ * 2;
  const size_t SZ_WOUT = (size_t)D_ * D_ * 2;
  const size_t SZ_T = (size_t)B_ * H_ * S_ * HD_ * 2;
  bf16* xb = (bf16*)(ws);
  bf16* wqkvb = (bf16*)(ws + SZ_X);
  bf16* woutb = (bf16*)(ws + SZ_X + SZ_WQKV);
  bf16* qws = (bf16*)(ws + SZ_X + SZ_WQKV + SZ_WOUT);
  bf16* kws = (bf16*)(ws + SZ_X + SZ_WQKV + SZ_WOUT + SZ_T);
  bf16* vtws = (bf16*)(ws + SZ_X + SZ_WQKV + SZ_WOUT + 2 * SZ_T);
  bf16* aob = (bf16*)(ws + SZ_X + SZ_WQKV + SZ_WOUT + 3 * SZ_T);

  const int NTOT4 = (NX_ + NW1_ + NW2_) / 4;
  k_cvt3<<<NTOT4 / 256, 256, 0, stream>>>(x, wqkv, wout, xb, wqkvb, woutb);

  k_qkv<<<dim3(64, 12), 512, 0, stream>>>(xb, wqkvb, qws, kws, vtws);
  k_attn<<<dim3(B_ * H_, 16), 512, 0, stream>>>(qws, kws, vtws, aob);
  k_outproj<<<dim3(64, 4), 512, 0, stream>>>(aob, woutb, out);
}

// Round 20
// 160.442 us; speedup vs baseline: 1.0541x; 1.0192x over previous
//
#include <hip/hip_runtime.h>
#include <hip/hip_bf16.h>

typedef __bf16 bf16x8 __attribute__((ext_vector_type(8)));
typedef float f32x4 __attribute__((ext_vector_type(4)));
typedef __hip_bfloat16 bf16;

#define B_ 4
#define S_ 2048
#define D_ 1024
#define H_ 16
#define HD_ 64

__device__ __forceinline__ void gload16(const bf16* g, bf16* l) {
  __builtin_amdgcn_global_load_lds(
      (const __attribute__((address_space(1))) unsigned int*)g,
      (__attribute__((address_space(3))) unsigned int*)l, 16, 0, 0);
}

#define MFMA16(a, b, c) __builtin_amdgcn_mfma_f32_16x16x32_bf16((a), (b), (c), 0, 0, 0)

// ---------------------------------------------------------------- cvt f32->bf16 (fused x, w_qkv, w_out)
#define NX_ (B_ * S_ * D_)
#define NW1_ (3 * D_ * D_)
#define NW2_ (D_ * D_)
__global__ __launch_bounds__(256) void k_cvt3(const float* __restrict__ x,
                                              const float* __restrict__ w1,
                                              const float* __restrict__ w2,
                                              bf16* __restrict__ ox,
                                              bf16* __restrict__ o1,
                                              bf16* __restrict__ o2) {
  int i = (blockIdx.x * 256 + threadIdx.x) * 4;
  const float* in;
  bf16* out;
  if (i < NX_) {
    in = x; out = ox;
  } else if (i < NX_ + NW1_) {
    in = w1; out = o1; i -= NX_;
  } else {
    in = w2; out = o2; i -= NX_ + NW1_;
  }
  float4 v = *reinterpret_cast<const float4*>(in + i);
  alignas(8) bf16 t[4];
  t[0] = __float2bfloat16(v.x);
  t[1] = __float2bfloat16(v.y);
  t[2] = __float2bfloat16(v.z);
  t[3] = __float2bfloat16(v.w);
  *reinterpret_cast<uint2*>(out + i) = *reinterpret_cast<uint2*>(t);
}

// ---------------------------------------------------------------- QKV GEMM (R13: interleaved counted-vmcnt)
__global__ __launch_bounds__(512) void k_qkv(const bf16* __restrict__ X,
                                             const bf16* __restrict__ W,
                                             bf16* __restrict__ Qw,
                                             bf16* __restrict__ Kw,
                                             bf16* __restrict__ Vtw) {
  __shared__ bf16 Al[2][128 * 64];  // 32 KB
  __shared__ bf16 Bl[2][256 * 64];  // 64 KB
  const int tid = threadIdx.x;
  const int wid = tid >> 6, lane = tid & 63, col = lane & 15, g = lane >> 4;
  const int wr = wid >> 2, wc = wid & 3;
  const int m0 = blockIdx.x * 128, n0 = blockIdx.y * 256;
  const int srow = tid >> 3;                 // 0..63
  const int scol = (tid & 7) * 8;
  const int csrc = scol ^ ((srow & 7) * 8);  // pre-swizzled source col
  const bf16* ga = X + (size_t)(m0 + srow) * 1024 + csrc;
  const bf16* gb = W + (size_t)(n0 + srow) * 1024 + csrc;
  const int ldst = srow * 64 + scol;         // linear LDS dest
  const int rsw = (col & 7) * 8;
  f32x4 acc[4][4] = {};
#define QKV_STAGE_ALL(buf, k0)                               \
  do {                                                       \
    gload16(ga + (k0), &Al[buf][ldst]);                      \
    gload16(ga + (k0) + 64 * 1024, &Al[buf][ldst + 4096]);   \
    gload16(gb + (k0), &Bl[buf][ldst]);                      \
    gload16(gb + (k0) + 64 * 1024, &Bl[buf][ldst + 4096]);   \
    gload16(gb + (k0) + 128 * 1024, &Bl[buf][ldst + 8192]);  \
    gload16(gb + (k0) + 192 * 1024, &Bl[buf][ldst + 12288]); \
  } while (0)
  QKV_STAGE_ALL(0, 0);
  QKV_STAGE_ALL(1, 64);
  for (int kt = 0; kt < 16; ++kt) {
    const int c = kt & 1;
    if (kt < 15)
      asm volatile("s_waitcnt vmcnt(6)" ::: "memory");
    else
      asm volatile("s_waitcnt vmcnt(0)" ::: "memory");
    __builtin_amdgcn_s_barrier();  // tile kt landed for all waves
    const bf16* Ac = Al[c];
    const bf16* Bc = Bl[c];
    bf16x8 af[2][4], bfr[2][4];
#pragma unroll
    for (int kk = 0; kk < 2; ++kk) {
      const int ce = (kk * 32 + g * 8) ^ rsw;
#pragma unroll
      for (int m = 0; m < 4; ++m)
        af[kk][m] =
            *reinterpret_cast<const bf16x8*>(&Ac[(wr * 64 + m * 16 + col) * 64 + ce]);
#pragma unroll
      for (int n = 0; n < 4; ++n)
        bfr[kk][n] =
            *reinterpret_cast<const bf16x8*>(&Bc[(wc * 64 + n * 16 + col) * 64 + ce]);
    }
    __builtin_amdgcn_s_setprio(1);
#pragma unroll
    for (int m = 0; m < 4; ++m) {
      acc[m][0] = MFMA16(af[0][m], bfr[0][0], acc[m][0]);
      acc[m][1] = MFMA16(af[0][m], bfr[0][1], acc[m][1]);
    }
    __builtin_amdgcn_s_setprio(0);
    asm volatile("s_waitcnt lgkmcnt(0)" ::: "memory");
    __builtin_amdgcn_sched_barrier(0);
    __builtin_amdgcn_s_barrier();  // all waves' reads of buf c complete -> free
    const bool more = (kt + 2 < 16);
    const int k2 = (kt + 2) * 64;
    if (more) {
      gload16(ga + k2, &Al[c][ldst]);
      gload16(ga + k2 + 64 * 1024, &Al[c][ldst + 4096]);
    }
    __builtin_amdgcn_s_setprio(1);
#pragma unroll
    for (int m = 0; m < 4; ++m) {
      acc[m][2] = MFMA16(af[0][m], bfr[0][2], acc[m][2]);
      acc[m][3] = MFMA16(af[0][m], bfr[0][3], acc[m][3]);
    }
    __builtin_amdgcn_s_setprio(0);
    if (more) {
      gload16(gb + k2, &Bl[c][ldst]);
      gload16(gb + k2 + 64 * 1024, &Bl[c][ldst + 4096]);
    }
    __builtin_amdgcn_s_setprio(1);
#pragma unroll
    for (int m = 0; m < 4; ++m) {
      acc[m][0] = MFMA16(af[1][m], bfr[1][0], acc[m][0]);
      acc[m][1] = MFMA16(af[1][m], bfr[1][1], acc[m][1]);
    }
    __builtin_amdgcn_s_setprio(0);
    if (more) {
      gload16(gb + k2 + 128 * 1024, &Bl[c][ldst + 8192]);
      gload16(gb + k2 + 192 * 1024, &Bl[c][ldst + 12288]);
    }
    __builtin_amdgcn_s_setprio(1);
#pragma unroll
    for (int m = 0; m < 4; ++m) {
      acc[m][2] = MFMA16(af[1][m], bfr[1][2], acc[m][2]);
      acc[m][3] = MFMA16(af[1][m], bfr[1][3], acc[m][3]);
    }
    __builtin_amdgcn_s_setprio(0);
  }
#undef QKV_STAGE_ALL
  const int e0 = n0 + wc * 64;
  const int which = e0 >> 10;
  const int h = (e0 >> 6) & 15;
  if (which == 2) {
#pragma unroll
    for (int m = 0; m < 4; ++m) {
      int mg = m0 + wr * 64 + m * 16 + g * 4;
      int b = mg >> 11, s = mg & 2047;
#pragma unroll
      for (int n = 0; n < 4; ++n) {
        int d = n * 16 + col;
        alignas(8) bf16 t[4];
#pragma unroll
        for (int r = 0; r < 4; ++r) t[r] = __float2bfloat16(acc[m][n][r]);
        *reinterpret_cast<uint2*>(&Vtw[((size_t)((b * 16 + h) * 64 + d) << 11) + s]) =
            *reinterpret_cast<uint2*>(t);
      }
    }
  } else {
    bf16* dst = which ? Kw : Qw;
    const float scale = which ? 1.0f : 0.18033688011112042f;  // 0.125*log2(e)
    const float fexp = -2.0f * 13.287712379549449f / 64.0f;
#pragma unroll
    for (int i = 0; i < 2; ++i) {
      int dlo = i * 16 + col;
      float invf = exp2f(fexp * (float)dlo);
#pragma unroll
      for (int m = 0; m < 4; ++m) {
        int mg = m0 + wr * 64 + m * 16 + g * 4;
        int b = mg >> 11;
        size_t rb = (size_t)(b * 16 + h) << 11;
#pragma unroll
        for (int r = 0; r < 4; ++r) {
          int s = (mg + r) & 2047;
          float sn, cs;
          __sincosf((float)s * invf, &sn, &cs);
          float lo = acc[m][i][r] * scale, hi = acc[m][i + 2][r] * scale;
          dst[((rb + s) << 6) + dlo] = __float2bfloat16(lo * cs - hi * sn);
          dst[((rb + s) << 6) + dlo + 32] = __float2bfloat16(hi * cs + lo * sn);
        }
      }
    }
  }
}

// ---------------------------------------------------------------- flash attention
// R16 winner (verbatim): gload_lds -> double-buffered K/V (linear stride 64,
// both-sides XOR swizzle), counted vmcnt(2), raw s_barrier, stage kt+2 after
// the consume barrier. Q fragments from global (one-time). P pad-72. 50KB.
__global__ __launch_bounds__(512) void k_attn(const bf16* __restrict__ Q,
                                              const bf16* __restrict__ K,
                                              const bf16* __restrict__ Vt,
                                              bf16* __restrict__ AO) {
  __shared__ bf16 Pl[128][72];     // per-wave P rows (pad-72, R13 layout)
  __shared__ bf16 Kl[2][64 * 64];  // [key][d], linear, swizzled content
  __shared__ bf16 Vl[2][64 * 64];  // [d][key], linear, swizzled content
  const int tid = threadIdx.x;
  const int wave = tid >> 6, lane = tid & 63, col = lane & 15, g = lane >> 4;
  const int bh = blockIdx.x;
  const size_t base = (size_t)bh << 17;
  const int r0 = tid >> 3, c0 = (tid & 7) * 8;   // r0: 0..63
  const int c0s = c0 ^ ((r0 & 7) * 8);           // pre-swizzled SOURCE col
  const int ldst = r0 * 64 + c0;                 // linear LDS dest (= tid*8)
  const int swc = (col & 7) * 8;                 // read-side XOR (row&7 == col&7)
  const int b = bh >> 4, h = bh & 15;
  // y -> qt mapping: quartets {y,y+4,y+8,y+12} sum to 30 (LPT-ordered too)
  const int yy = blockIdx.y, a = yy >> 2, r_ = yy & 3;
  const int qt = (a == 0) ? (15 - r_) : (a == 1) ? (8 + (r_ ^ 2)) : (a == 2) ? (4 + (r_ ^ 1)) : r_;
  const int q0 = qt * 128;
  const int qw = q0 + wave * 16;
  const int q = qw + col;
  // Q fragments straight from global (one-time)
  const bf16* Qp = Q + base + (size_t)q * 64 + g * 8;
  bf16x8 qf[2];
  qf[0] = *reinterpret_cast<const bf16x8*>(Qp);
  qf[1] = *reinterpret_cast<const bf16x8*>(Qp + 32);
  const int ktlim = 2 * qt + 1;      // block-wide last tile (incl.)
  const int ktmax = (qw + 15) >> 6;  // this wave's last useful tile
  const bf16* Ks = K + base + c0s;
  const bf16* Vs = Vt + base + (size_t)r0 * 2048 + c0s;
#define ATT_STAGE(buf, k0)                                  \
  do {                                                      \
    gload16(Ks + (size_t)((k0) + r0) * 64, &Kl[buf][ldst]); \
    gload16(Vs + (k0), &Vl[buf][ldst]);                     \
  } while (0)
  // prologue: tiles 0 and 1
  ATT_STAGE(0, 0);
  ATT_STAGE(1, 64);
  float l_s = 0.0f;
  f32x4 o[4] = {};
  for (int kt = 0; kt <= ktlim; ++kt) {
    const int c = kt & 1;
    const int k0 = kt * 64;
    if (kt < ktlim)
      asm volatile("s_waitcnt vmcnt(2)" ::: "memory");
    else
      asm volatile("s_waitcnt vmcnt(0)" ::: "memory");
    __builtin_amdgcn_s_barrier();  // tile kt landed for all waves
    if (kt <= ktmax) {
      const bool needmask = (k0 + 63 > qw);  // wave-uniform
      __builtin_amdgcn_s_setprio(1);
#pragma unroll
      for (int n = 0; n < 4; ++n) {
        f32x4 s = {};
#pragma unroll
        for (int kk = 0; kk < 2; ++kk) {
          bf16x8 kf = *reinterpret_cast<const bf16x8*>(
              &Kl[c][(n * 16 + col) * 64 + ((g * 8 + kk * 32) ^ swc)]);
          s = MFMA16(kf, qf[kk], s);
        }
        if (needmask) {
#pragma unroll
          for (int r = 0; r < 4; ++r)
            if (k0 + n * 16 + g * 4 + r > q) s[r] = -3e38f;
        }
        alignas(8) bf16 t[4];
#pragma unroll
        for (int r = 0; r < 4; ++r) {
          float p = exp2f(s[r]);
          l_s += p;
          t[r] = __float2bfloat16(p);
        }
        *reinterpret_cast<uint2*>(&Pl[wave * 16 + col][n * 16 + g * 4]) =
            *reinterpret_cast<uint2*>(t);
      }
      // O += P V   (P wave-private)
#pragma unroll
      for (int kk = 0; kk < 2; ++kk) {
        bf16x8 pf =
            *reinterpret_cast<const bf16x8*>(&Pl[wave * 16 + col][g * 8 + kk * 32]);
#pragma unroll
        for (int n2 = 0; n2 < 4; ++n2) {
          bf16x8 vf = *reinterpret_cast<const bf16x8*>(
              &Vl[c][(n2 * 16 + col) * 64 + ((g * 8 + kk * 32) ^ swc)]);
          o[n2] = MFMA16(pf, vf, o[n2]);
        }
      }
      __builtin_amdgcn_s_setprio(0);
    }
    __builtin_amdgcn_s_barrier();  // all waves done reading buf c
    if (kt + 2 <= ktlim) ATT_STAGE(c, k0 + 128);
  }
#undef ATT_STAGE
  l_s += __shfl_xor(l_s, 16);
  l_s += __shfl_xor(l_s, 32);
#pragma unroll
  for (int r = 0; r < 4; ++r) {
    float inv = 1.0f / __shfl(l_s, (lane & 48) | (g * 4 + r));
    int s = qw + g * 4 + r;
#pragma unroll
    for (int n2 = 0; n2 < 4; ++n2)
      AO[((size_t)(b * 2048 + s) << 10) + h * 64 + n2 * 16 + col] =
          __float2bfloat16(o[n2][r] * inv);
  }
}

// ---------------------------------------------------------------- out projection (R13: interleaved counted-vmcnt)
__global__ __launch_bounds__(512) void k_outproj(const bf16* __restrict__ A,
                                                 const bf16* __restrict__ W,
                                                 float* __restrict__ OUT) {
  __shared__ bf16 Al[2][128 * 64];
  __shared__ bf16 Bl[2][256 * 64];
  const int tid = threadIdx.x;
  const int wid = tid >> 6, lane = tid & 63, col = lane & 15, g = lane >> 4;
  const int wr = wid >> 2, wc = wid & 3;
  const int m0 = blockIdx.x * 128, n0 = blockIdx.y * 256;
  const int srow = tid >> 3;
  const int scol = (tid & 7) * 8;
  const int csrc = scol ^ ((srow & 7) * 8);
  const bf16* ga = A + (size_t)(m0 + srow) * 1024 + csrc;
  const bf16* gb = W + (size_t)(n0 + srow) * 1024 + csrc;
  const int ldst = srow * 64 + scol;
  const int rsw = (col & 7) * 8;
  f32x4 acc[4][4] = {};
#define OP_STAGE_ALL(buf, k0)                                \
  do {                                                       \
    gload16(ga + (k0), &Al[buf][ldst]);                      \
    gload16(ga + (k0) + 64 * 1024, &Al[buf][ldst + 4096]);   \
    gload16(gb + (k0), &Bl[buf][ldst]);                      \
    gload16(gb + (k0) + 64 * 1024, &Bl[buf][ldst + 4096]);   \
    gload16(gb + (k0) + 128 * 1024, &Bl[buf][ldst + 8192]);  \
    gload16(gb + (k0) + 192 * 1024, &Bl[buf][ldst + 12288]); \
  } while (0)
  OP_STAGE_ALL(0, 0);
  OP_STAGE_ALL(1, 64);
  for (int kt = 0; kt < 16; ++kt) {
    const int c = kt & 1;
    if (kt < 15)
      asm volatile("s_waitcnt vmcnt(6)" ::: "memory");
    else
      asm volatile("s_waitcnt vmcnt(0)" ::: "memory");
    __builtin_amdgcn_s_barrier();
    const bf16* Ac = Al[c];
    const bf16* Bc = Bl[c];
    bf16x8 af[2][4], bfr[2][4];
#pragma unroll
    for (int kk = 0; kk < 2; ++kk) {
      const int ce = (kk * 32 + g * 8) ^ rsw;
#pragma unroll
      for (int m = 0; m < 4; ++m)
        af[kk][m] =
            *reinterpret_cast<const bf16x8*>(&Ac[(wr * 64 + m * 16 + col) * 64 + ce]);
#pragma unroll
      for (int n = 0; n < 4; ++n)
        bfr[kk][n] =
            *reinterpret_cast<const bf16x8*>(&Bc[(wc * 64 + n * 16 + col) * 64 + ce]);
    }
    __builtin_amdgcn_s_setprio(1);
#pragma unroll
    for (int m = 0; m < 4; ++m) {
      acc[m][0] = MFMA16(af[0][m], bfr[0][0], acc[m][0]);
      acc[m][1] = MFMA16(af[0][m], bfr[0][1], acc[m][1]);
    }
    __builtin_amdgcn_s_setprio(0);
    asm volatile("s_waitcnt lgkmcnt(0)" ::: "memory");
    __builtin_amdgcn_sched_barrier(0);
    __builtin_amdgcn_s_barrier();
    const bool more = (kt + 2 < 16);
    const int k2 = (kt + 2) * 64;
    if (more) {
      gload16(ga + k2, &Al[c][ldst]);
      gload16(ga + k2 + 64 * 1024, &Al[c][ldst + 4096]);
    }
    __builtin_amdgcn_s_setprio(1);
#pragma unroll
    for (int m = 0; m < 4; ++m) {
      acc[m][2] = MFMA16(af[0][m], bfr[0][2], acc[m][2]);
      acc[m][3] = MFMA16(af[0][m], bfr[0][3], acc[m][3]);
    }
    __builtin_amdgcn_s_setprio(0);
    if (more) {
      gload16(gb + k2, &Bl[c][ldst]);
      gload16(gb + k2 + 64 * 1024, &Bl[c][ldst + 4096]);
    }
    __builtin_amdgcn_s_setprio(1);
#pragma unroll
    for (int m = 0; m < 4; ++m) {
      acc[m][0] = MFMA16(af[1][m], bfr[1][0], acc[m][0]);
      acc[m][1] = MFMA16(af[1][m], bfr[1][1], acc[m][1]);
    }
    __builtin_amdgcn_s_setprio(0);
    if (more) {
      gload16(gb + k2 + 128 * 1024, &Bl[c][ldst + 8192]);
      gload16(gb + k2 + 192 * 1024, &Bl[c][ldst + 12288]);
    }
    __builtin_amdgcn_s_setprio(1);
#pragma unroll
    for (int m = 0; m < 4; ++m) {
      acc[m][2] = MFMA16(af[1][m], bfr[1][2], acc[m][2]);
      acc[m][3] = MFMA16(af[1][m], bfr[1][3], acc[m][3]);
    }
    __builtin_amdgcn_s_setprio(0);
  }
#undef OP_STAGE_ALL
#pragma unroll
  for (int m = 0; m < 4; ++m)
#pragma unroll
    for (int n = 0; n < 4; ++n)
#pragma unroll
      for (int r = 0; r < 4; ++r)
        OUT[(size_t)(m0 + wr * 64 + m * 16 + g * 4 + r) * 1024 + n0 + wc * 64 + n * 16 +
            col] = acc[m][n][r];
}

// ---------------------------------------------------------------- launcher
extern "C" void kernel_launch(void* const* d_in, const int* in_sizes, int n_in,
                              void* d_out, int out_size, void* d_ws, size_t ws_size,
                              hipStream_t stream) {
  const float* x = (const float*)d_in[0];
  const float* wqkv = (const float*)d_in[1];
  const float* wout = (const float*)d_in[2];
  float* out = (float*)d_out;

  char* ws = (char*)d_ws;
  const size_t SZ_X = (size_t)B_ * S_ * D_ * 2;
  const size_t SZ_WQKV = (size_t)3 * D_ * D_ * 2;
  const size_t SZ_WOUT = (size_t)D_ * D_ * 2;
  const size_t SZ_T = (size_t)B_ * H_ * S_ * HD_ * 2;
  bf16* xb = (bf16*)(ws);
  bf16* wqkvb = (bf16*)(ws + SZ_X);
  bf16* woutb = (bf16*)(ws + SZ_X + SZ_WQKV);
  bf16* qws = (bf16*)(ws + SZ_X + SZ_WQKV + SZ_WOUT);
  bf16* kws = (bf16*)(ws + SZ_X + SZ_WQKV + SZ_WOUT + SZ_T);
  bf16* vtws = (bf16*)(ws + SZ_X + SZ_WQKV + SZ_WOUT + 2 * SZ_T);
  bf16* aob = (bf16*)(ws + SZ_X + SZ_WQKV + SZ_WOUT + 3 * SZ_T);

  const int NTOT4 = (NX_ + NW1_ + NW2_) / 4;
  k_cvt3<<<NTOT4 / 256, 256, 0, stream>>>(x, wqkv, wout, xb, wqkvb, woutb);

  k_qkv<<<dim3(64, 12), 512, 0, stream>>>(xb, wqkvb, qws, kws, vtws);
  k_attn<<<dim3(B_ * H_, 16), 512, 0, stream>>>(qws, kws, vtws, aob);
  k_outproj<<<dim3(64, 4), 512, 0, stream>>>(aob, woutb, out);
}